// Round 1
// baseline (2010.797 us; speedup 1.0000x reference)
//
#include <hip/hip_runtime.h>

typedef unsigned short u16;
typedef unsigned int u32;
typedef __bf16 bf16x8 __attribute__((ext_vector_type(8)));
typedef float f32x4 __attribute__((ext_vector_type(4)));

// Problem constants (fixed by reference): B=4, T=8192, C=2048, H=16, dh=128, BLOCK=128
#define DIM_M 32768      // B*T
#define DIM_C 2048
#define DIM_3C 6144
#define N_HEAD 16
#define DH 128

__device__ __forceinline__ u16 f2bf(float f) {
  u32 x = __float_as_uint(f);
  u32 r = x + 0x7fffu + ((x >> 16) & 1u);  // RNE
  return (u16)(r >> 16);
}

__device__ __forceinline__ void async_copy16(const void* g, void* l) {
  __builtin_amdgcn_global_load_lds((const __attribute__((address_space(1))) u32*)g,
                                   (__attribute__((address_space(3))) u32*)l,
                                   16, 0, 0);
}

// ---------------- fp32 -> bf16 elementwise convert (x) ----------------
__global__ __launch_bounds__(256) void cvt_f32_bf16(const float* __restrict__ in,
                                                    u16* __restrict__ out) {
  size_t i = ((size_t)blockIdx.x * 256 + threadIdx.x) * 4;
  float4 v = *(const float4*)(in + i);
  union { u16 s[4]; uint2 u; } o;
  o.s[0] = f2bf(v.x); o.s[1] = f2bf(v.y); o.s[2] = f2bf(v.z); o.s[3] = f2bf(v.w);
  *(uint2*)(out + i) = o.u;
}

// ------------- fp32 KxN -> bf16 NxK transpose-convert (weights) -------------
__global__ __launch_bounds__(256) void transpose_cvt(const float* __restrict__ W,
                                                     u16* __restrict__ Wt,
                                                     int K, int N) {
  __shared__ u16 t[32][33];
  int nb = blockIdx.x * 32, kb = blockIdx.y * 32;
  int r = threadIdx.x >> 5, c = threadIdx.x & 31;
#pragma unroll
  for (int i = 0; i < 4; ++i) {
    int rr = i * 8 + r;
    t[rr][c] = f2bf(W[(size_t)(kb + rr) * N + nb + c]);
  }
  __syncthreads();
#pragma unroll
  for (int i = 0; i < 4; ++i) {
    int rr = i * 8 + r;
    Wt[(size_t)(nb + rr) * K + kb + c] = t[c][rr];
  }
}

// ---------------- m97-style bf16 GEMM, B^T input (both K-major) ----------------
// C[M,N] = A[M,K] * Bt[N,K]^T ; 128x128 tile, BK=32, 256 threads (4 waves, 64x64/wave)
template <bool OUT_BF16>
__global__ __launch_bounds__(256) void gemm_bt(const u16* __restrict__ A,
                                               const u16* __restrict__ Bt,
                                               void* __restrict__ Cv,
                                               int M, int N, int K) {
  __shared__ u16 As[128 * 32];
  __shared__ u16 Bs[128 * 32];
  const int tid = threadIdx.x;
  const int wave = tid >> 6;
  const int lane = tid & 63;
  const int ln15 = lane & 15;
  const int quad = lane >> 4;
  const int srow = lane >> 2;        // 16 rows per 1KB chunk, 4 lanes/row
  const int scol = (lane & 3) * 8;   // 8 bf16 (16B) per lane
  const int rowblk = blockIdx.y * 128;
  const int colblk = blockIdx.x * 128;
  const int wr = (wave >> 1) * 64;
  const int wc = (wave & 1) * 64;

  f32x4 acc[4][4] = {};

  const int ch0 = wave, ch1 = wave + 4;
  const u16* ga0 = A + (size_t)(rowblk + ch0 * 16 + srow) * K + scol;
  const u16* ga1 = A + (size_t)(rowblk + ch1 * 16 + srow) * K + scol;
  const u16* gb0 = Bt + (size_t)(colblk + ch0 * 16 + srow) * K + scol;
  const u16* gb1 = Bt + (size_t)(colblk + ch1 * 16 + srow) * K + scol;

  for (int kt = 0; kt < K; kt += 32) {
    __syncthreads();
    async_copy16(ga0 + kt, &As[ch0 * 512]);
    async_copy16(ga1 + kt, &As[ch1 * 512]);
    async_copy16(gb0 + kt, &Bs[ch0 * 512]);
    async_copy16(gb1 + kt, &Bs[ch1 * 512]);
    __syncthreads();
    bf16x8 a[4], b[4];
#pragma unroll
    for (int i = 0; i < 4; ++i)
      a[i] = *(const bf16x8*)&As[(wr + i * 16 + ln15) * 32 + quad * 8];
#pragma unroll
    for (int j = 0; j < 4; ++j)
      b[j] = *(const bf16x8*)&Bs[(wc + j * 16 + ln15) * 32 + quad * 8];
#pragma unroll
    for (int i = 0; i < 4; ++i)
#pragma unroll
      for (int j = 0; j < 4; ++j)
        acc[i][j] = __builtin_amdgcn_mfma_f32_16x16x32_bf16(a[i], b[j], acc[i][j], 0, 0, 0);
  }

#pragma unroll
  for (int i = 0; i < 4; ++i) {
#pragma unroll
    for (int j = 0; j < 4; ++j) {
      const float* ap = (const float*)&acc[i][j];
#pragma unroll
      for (int r = 0; r < 4; ++r) {
        int row = rowblk + wr + i * 16 + quad * 4 + r;  // C/D: row=(lane>>4)*4+reg
        int col = colblk + wc + j * 16 + ln15;          //      col=lane&15
        if (OUT_BF16)
          ((u16*)Cv)[(size_t)row * N + col] = f2bf(ap[r]);
        else
          ((float*)Cv)[(size_t)row * N + col] = ap[r];
      }
    }
  }
}

// ---------------- block-local causal attention ----------------
// one workgroup per (b, seg, head): S=QK^T/sqrt(dh), causal softmax, O=PV
// LDS: buf0 = Q (later P), buf1 = K (later V^T); XOR-swizzled 16B chunks.
__global__ __launch_bounds__(256) void attn_block(const u16* __restrict__ qkv,
                                                  u16* __restrict__ y) {
  __shared__ u16 buf0[128 * 128];  // Q -> P
  __shared__ u16 buf1[128 * 128];  // K -> V^T
  const int h = blockIdx.x, n = blockIdx.y, b = blockIdx.z;
  const size_t rowbase = ((size_t)b * 8192 + (size_t)n * 128) * DIM_3C;
  const int qcol = h * DH, kcol = DIM_C + h * DH, vcol = 2 * DIM_C + h * DH;
  const int tid = threadIdx.x;
  const int wave = tid >> 6, lane = tid & 63;
  const int ln15 = lane & 15, quad = lane >> 4;
  const int r0 = wave * 32;

  // stage Q and K (swizzled: elem (row,d) at row*128 + ((d>>3)^(row&15))*8 + (d&7))
#pragma unroll
  for (int it = 0; it < 16; ++it) {
    int f = tid + it * 256;   // 0..4095
    int tk = f >> 5;          // 0..127
    int dg = f & 31;          // d = dg*4
    int off = tk * 128 + (((dg >> 1) ^ (tk & 15)) * 8) + (dg & 1) * 4;
    uint2 qv = *(const uint2*)(qkv + rowbase + (size_t)tk * DIM_3C + qcol + dg * 4);
    *(uint2*)(buf0 + off) = qv;
    uint2 kv = *(const uint2*)(qkv + rowbase + (size_t)tk * DIM_3C + kcol + dg * 4);
    *(uint2*)(buf1 + off) = kv;
  }
  __syncthreads();

  // S = Q K^T : wave handles rows r0..r0+31, all 128 cols
  f32x4 acc[2][8] = {};
#pragma unroll
  for (int ks = 0; ks < 4; ++ks) {
    bf16x8 aq[2], bk[8];
#pragma unroll
    for (int i = 0; i < 2; ++i) {
      int row = r0 + i * 16 + ln15;
      aq[i] = *(const bf16x8*)(buf0 + row * 128 + (((ks * 4 + quad) ^ (row & 15)) * 8));
    }
#pragma unroll
    for (int j = 0; j < 8; ++j) {
      int row = j * 16 + ln15;
      bk[j] = *(const bf16x8*)(buf1 + row * 128 + (((ks * 4 + quad) ^ (row & 15)) * 8));
    }
#pragma unroll
    for (int i = 0; i < 2; ++i)
#pragma unroll
      for (int j = 0; j < 8; ++j)
        acc[i][j] = __builtin_amdgcn_mfma_f32_16x16x32_bf16(aq[i], bk[j], acc[i][j], 0, 0, 0);
  }

  // masked softmax over full row (held across 8 j-tiles x 16 lanes of the quad)
  const float scale = 0.08838834764831845f;  // 1/sqrt(128)
  float lrow[2][4];
#pragma unroll
  for (int i = 0; i < 2; ++i) {
#pragma unroll
    for (int r = 0; r < 4; ++r) {
      int row = r0 + i * 16 + quad * 4 + r;
      float m = -1e30f;
#pragma unroll
      for (int j = 0; j < 8; ++j) {
        float* ap = (float*)&acc[i][j];
        int col = j * 16 + ln15;
        float s = ap[r] * scale;
        if (col > row) s = -1e30f;
        ap[r] = s;
        m = fmaxf(m, s);
      }
#pragma unroll
      for (int off = 1; off < 16; off <<= 1) m = fmaxf(m, __shfl_xor(m, off));
      float l = 0.f;
#pragma unroll
      for (int j = 0; j < 8; ++j) {
        float* ap = (float*)&acc[i][j];
        float p = __expf(ap[r] - m);
        ap[r] = p;
        l += p;
      }
#pragma unroll
      for (int off = 1; off < 16; off <<= 1) l += __shfl_xor(l, off);
      lrow[i][r] = l;
    }
  }
  __syncthreads();  // all waves done reading Q/K tiles

  // write P (bf16, swizzled) into buf0; stage V^T into buf1
#pragma unroll
  for (int i = 0; i < 2; ++i)
#pragma unroll
    for (int j = 0; j < 8; ++j) {
      const float* ap = (const float*)&acc[i][j];
#pragma unroll
      for (int r = 0; r < 4; ++r) {
        int row = r0 + i * 16 + quad * 4 + r;
        int col = j * 16 + ln15;
        buf0[row * 128 + (((col >> 3) ^ (row & 15)) * 8) + (col & 7)] = f2bf(ap[r]);
      }
    }
#pragma unroll
  for (int it = 0; it < 16; ++it) {
    int f = tid + it * 256;
    int tk = f >> 5;
    int dg = f & 31;
    uint2 vv = *(const uint2*)(qkv + rowbase + (size_t)tk * DIM_3C + vcol + dg * 4);
    union { u16 s[4]; uint2 u; } tmp;
    tmp.u = vv;
#pragma unroll
    for (int j = 0; j < 4; ++j) {
      int dd = dg * 4 + j;  // V^T element (dd, tk)
      buf1[dd * 128 + (((tk >> 3) ^ (dd & 15)) * 8) + (tk & 7)] = tmp.s[j];
    }
  }
  __syncthreads();

  // O = P V : rows r0..r0+31, d = 0..127
  f32x4 accO[2][8] = {};
#pragma unroll
  for (int ks = 0; ks < 4; ++ks) {
    bf16x8 ap[2], bv[8];
#pragma unroll
    for (int i = 0; i < 2; ++i) {
      int row = r0 + i * 16 + ln15;
      ap[i] = *(const bf16x8*)(buf0 + row * 128 + (((ks * 4 + quad) ^ (row & 15)) * 8));
    }
#pragma unroll
    for (int j = 0; j < 8; ++j) {
      int row = j * 16 + ln15;  // d-row of V^T
      bv[j] = *(const bf16x8*)(buf1 + row * 128 + (((ks * 4 + quad) ^ (row & 15)) * 8));
    }
#pragma unroll
    for (int i = 0; i < 2; ++i)
#pragma unroll
      for (int j = 0; j < 8; ++j)
        accO[i][j] = __builtin_amdgcn_mfma_f32_16x16x32_bf16(ap[i], bv[j], accO[i][j], 0, 0, 0);
  }

  u16* yb = y + ((size_t)b * 8192 + (size_t)n * 128) * DIM_C + h * DH;
#pragma unroll
  for (int i = 0; i < 2; ++i)
#pragma unroll
    for (int j = 0; j < 8; ++j) {
      const float* op = (const float*)&accO[i][j];
#pragma unroll
      for (int r = 0; r < 4; ++r) {
        int row = r0 + i * 16 + quad * 4 + r;
        int col = j * 16 + ln15;
        yb[(size_t)row * DIM_C + col] = f2bf(op[r] / lrow[i][r]);
      }
    }
}

extern "C" void kernel_launch(void* const* d_in, const int* in_sizes, int n_in,
                              void* d_out, int out_size, void* d_ws, size_t ws_size,
                              hipStream_t stream) {
  const float* x = (const float*)d_in[0];       // (4,8192,2048)
  const float* W_qkv = (const float*)d_in[1];   // (2048,6144)
  const float* W_proj = (const float*)d_in[2];  // (2048,2048)
  float* out = (float*)d_out;                   // (4,8192,2048) fp32

  char* ws = (char*)d_ws;
  // layout: [xb (aliased by yb) 128MiB][qkvb 384MiB][Wqt 24MiB][Wpt 8MiB] = 544MiB
  u16* xb = (u16*)ws;                                       // 32768*2048
  u16* yb = xb;                                             // alias: x dead after GEMM1
  u16* qkvb = (u16*)(ws + (size_t)134217728);               // 32768*6144
  u16* Wqt = (u16*)(ws + (size_t)134217728 + 402653184);    // 6144*2048
  u16* Wpt = Wqt + (size_t)6144 * 2048;                     // 2048*2048

  // 1. convert x -> bf16 (67.1M elems, 16.78M float4)
  cvt_f32_bf16<<<dim3(65536), dim3(256), 0, stream>>>(x, xb);
  // 2. weights -> bf16, transposed to N x K
  transpose_cvt<<<dim3(DIM_3C / 32, DIM_C / 32), dim3(256), 0, stream>>>(W_qkv, Wqt, DIM_C, DIM_3C);
  transpose_cvt<<<dim3(DIM_C / 32, DIM_C / 32), dim3(256), 0, stream>>>(W_proj, Wpt, DIM_C, DIM_C);
  // 3. qkv = x @ W_qkv  (bf16 out)
  gemm_bt<true><<<dim3(DIM_3C / 128, DIM_M / 128), dim3(256), 0, stream>>>(
      xb, Wqt, (void*)qkvb, DIM_M, DIM_3C, DIM_C);
  // 4. block-local causal attention -> y (bf16)
  attn_block<<<dim3(N_HEAD, 64, 4), dim3(256), 0, stream>>>(qkvb, yb);
  // 5. out = y @ W_proj (fp32 out)
  gemm_bt<false><<<dim3(DIM_C / 128, DIM_M / 128), dim3(256), 0, stream>>>(
      yb, Wpt, (void*)out, DIM_M, DIM_C, DIM_C);
}